// Round 7
// baseline (219.392 us; speedup 1.0000x reference)
//
#include <hip/hip_runtime.h>
#include <hip/hip_bf16.h>

#define DD 64
#define NEG_SLOPE 0.2f
#define HS 68          // padded LDS stride for h tile
#define BSH 8          // bucket = dst >> 8 (256 nodes per bucket)
#define BN  256        // nodes per bucket
#define NBMAX 256      // max buckets supported by LDS hists
#define NBLK 256       // edge-chunk blocks for the multi-split
#define STAGE_CAP 6144 // LDS col staging per bucket (expected ~4096 edges)

// fp32 -> bf16 round-to-nearest-even (finite inputs)
__device__ __forceinline__ unsigned short f2bf(float f)
{
    unsigned u = __float_as_uint(f);
    u += 0x7FFFu + ((u >> 16) & 1u);
    return (unsigned short)(u >> 16);
}

// ---------------------------------------------------------------------------
// K1 (fused, disjoint block ranges):
//   blocks [0, NBLK)            : chunk_count — per-chunk bucket histogram
//   blocks [NBLK, NBLK+mm_tiles): mm_fused   — h = relu(x@W0+b0); hx(bf16)=h@W1;
//                                              sarr/darr = hx.a_src / hx.a_dst
// ---------------------------------------------------------------------------
__global__ __launch_bounds__(256) void k1_count_mm(
    const int4* __restrict__ dst4, const int* __restrict__ dst,
    int* __restrict__ cnts, int NB, int E4, int E, int C4,
    const float* __restrict__ x,
    const float* __restrict__ W0, const float* __restrict__ b0,
    const float* __restrict__ W1,
    const float* __restrict__ a_src, const float* __restrict__ a_dst,
    float* __restrict__ h, ushort4* __restrict__ hxb4,
    float* __restrict__ sarr, float* __restrict__ darr, int n)
{
    __shared__ float Wsh[DD * DD];
    __shared__ float Hsh[DD * HS];
    int tid = threadIdx.x;

    if (blockIdx.x < NBLK) {
        // ---- chunk_count path ----
        int* lh = (int*)Wsh;
        int k = blockIdx.x;
        for (int i = tid; i < NB; i += 256) lh[i] = 0;
        __syncthreads();
        int i0 = k * C4, i1 = min(i0 + C4, E4);
        for (int i = i0 + tid; i < i1; i += 256) {
            int4 d = dst4[i];
            atomicAdd(&lh[d.x >> BSH], 1);
            atomicAdd(&lh[d.y >> BSH], 1);
            atomicAdd(&lh[d.z >> BSH], 1);
            atomicAdd(&lh[d.w >> BSH], 1);
        }
        if (k == NBLK - 1) {
            for (int e = E4 * 4 + tid; e < E; e += 256)
                atomicAdd(&lh[dst[e] >> BSH], 1);
        }
        __syncthreads();
        for (int i = tid; i < NB; i += 256) cnts[k * NB + i] = lh[i];
        return;
    }

    // ---- mm_fused path ----
    for (int i = tid * 4; i < DD * DD; i += 1024)
        *(float4*)&Wsh[i] = *(const float4*)&W0[i];

    int fg = tid & 15, ng = tid >> 4;
    int tile0 = (blockIdx.x - NBLK) * 64;
    for (int p = 0; p < 4; ++p) {
        int nl = p * 16 + ng, gn = tile0 + nl;
        if (gn < n)
            *(float4*)&Hsh[nl * HS + 4 * fg] = *(const float4*)&x[gn * DD + 4 * fg];
    }
    __syncthreads();

    float4 acc[4];
#pragma unroll
    for (int j = 0; j < 4; ++j) acc[j] = float4{0.f, 0.f, 0.f, 0.f};
#pragma unroll 8
    for (int k = 0; k < DD; ++k) {
        float4 w4 = *(float4*)&Wsh[k * DD + 4 * fg];
#pragma unroll
        for (int j = 0; j < 4; ++j) {
            float hv = Hsh[(4 * ng + j) * HS + k];
            acc[j].x += hv * w4.x; acc[j].y += hv * w4.y;
            acc[j].z += hv * w4.z; acc[j].w += hv * w4.w;
        }
    }

    float4 b4 = *(const float4*)&b0[4 * fg];
    float4 o[4];
#pragma unroll
    for (int j = 0; j < 4; ++j) {
        o[j].x = fmaxf(acc[j].x + b4.x, 0.f);
        o[j].y = fmaxf(acc[j].y + b4.y, 0.f);
        o[j].z = fmaxf(acc[j].z + b4.z, 0.f);
        o[j].w = fmaxf(acc[j].w + b4.w, 0.f);
        int gn = tile0 + 4 * ng + j;
        if (gn < n) *(float4*)&h[gn * DD + 4 * fg] = o[j];
    }
    __syncthreads();

#pragma unroll
    for (int j = 0; j < 4; ++j)
        *(float4*)&Hsh[(4 * ng + j) * HS + 4 * fg] = o[j];
    for (int i = tid * 4; i < DD * DD; i += 1024)
        *(float4*)&Wsh[i] = *(const float4*)&W1[i];
    __syncthreads();

#pragma unroll
    for (int j = 0; j < 4; ++j) acc[j] = float4{0.f, 0.f, 0.f, 0.f};
#pragma unroll 8
    for (int k = 0; k < DD; ++k) {
        float4 w4 = *(float4*)&Wsh[k * DD + 4 * fg];
#pragma unroll
        for (int j = 0; j < 4; ++j) {
            float hv = Hsh[(4 * ng + j) * HS + k];
            acc[j].x += hv * w4.x; acc[j].y += hv * w4.y;
            acc[j].z += hv * w4.z; acc[j].w += hv * w4.w;
        }
    }

    float4 as4 = *(const float4*)&a_src[4 * fg];
    float4 ad4 = *(const float4*)&a_dst[4 * fg];
#pragma unroll
    for (int j = 0; j < 4; ++j) {
        int gn = tile0 + 4 * ng + j;
        if (gn < n) {
            ushort4 hb;
            hb.x = f2bf(acc[j].x); hb.y = f2bf(acc[j].y);
            hb.z = f2bf(acc[j].z); hb.w = f2bf(acc[j].w);
            hxb4[gn * 16 + fg] = hb;
        }
        float ps = acc[j].x * as4.x + acc[j].y * as4.y + acc[j].z * as4.z + acc[j].w * as4.w;
        float pd = acc[j].x * ad4.x + acc[j].y * ad4.y + acc[j].z * ad4.z + acc[j].w * ad4.w;
#pragma unroll
        for (int off = 8; off; off >>= 1) {
            ps += __shfl_xor(ps, off);
            pd += __shfl_xor(pd, off);
        }
        if (fg == 0 && gn < n) { sarr[gn] = ps; darr[gn] = pd; }
    }
}

// ---------------------------------------------------------------------------
// Plain GAT matmul (layer 2), hx output in bf16
// ---------------------------------------------------------------------------
__global__ __launch_bounds__(256) void mm_gat(
    const float* __restrict__ h, const float* __restrict__ W,
    const float* __restrict__ a_src, const float* __restrict__ a_dst,
    ushort4* __restrict__ hxb4, float* __restrict__ sarr, float* __restrict__ darr,
    int n)
{
    __shared__ float Wsh[DD * DD];
    __shared__ float Hsh[DD * HS];
    int tid = threadIdx.x;
    for (int i = tid * 4; i < DD * DD; i += 1024)
        *(float4*)&Wsh[i] = *(const float4*)&W[i];

    int fg = tid & 15, ng = tid >> 4;
    int tile0 = blockIdx.x * 64;
    for (int p = 0; p < 4; ++p) {
        int nl = p * 16 + ng, gn = tile0 + nl;
        if (gn < n)
            *(float4*)&Hsh[nl * HS + 4 * fg] = *(const float4*)&h[gn * DD + 4 * fg];
    }
    __syncthreads();

    float4 acc[4];
#pragma unroll
    for (int j = 0; j < 4; ++j) acc[j] = float4{0.f, 0.f, 0.f, 0.f};
#pragma unroll 8
    for (int k = 0; k < DD; ++k) {
        float4 w4 = *(float4*)&Wsh[k * DD + 4 * fg];
#pragma unroll
        for (int j = 0; j < 4; ++j) {
            float hv = Hsh[(4 * ng + j) * HS + k];
            acc[j].x += hv * w4.x; acc[j].y += hv * w4.y;
            acc[j].z += hv * w4.z; acc[j].w += hv * w4.w;
        }
    }

    float4 as4 = *(const float4*)&a_src[4 * fg];
    float4 ad4 = *(const float4*)&a_dst[4 * fg];
#pragma unroll
    for (int j = 0; j < 4; ++j) {
        int gn = tile0 + 4 * ng + j;
        if (gn < n) {
            ushort4 hb;
            hb.x = f2bf(acc[j].x); hb.y = f2bf(acc[j].y);
            hb.z = f2bf(acc[j].z); hb.w = f2bf(acc[j].w);
            hxb4[gn * 16 + fg] = hb;
        }
        float ps = acc[j].x * as4.x + acc[j].y * as4.y + acc[j].z * as4.z + acc[j].w * as4.w;
        float pd = acc[j].x * ad4.x + acc[j].y * ad4.y + acc[j].z * ad4.z + acc[j].w * ad4.w;
#pragma unroll
        for (int off = 8; off; off >>= 1) {
            ps += __shfl_xor(ps, off);
            pd += __shfl_xor(pd, off);
        }
        if (fg == 0 && gn < n) { sarr[gn] = ps; darr[gn] = pd; }
    }
}

// ---------------------------------------------------------------------------
// CSR build — privatized multi-split (no global atomics, deterministic)
// ---------------------------------------------------------------------------
__device__ __forceinline__ int wave_incl_scan(int v, int lane)
{
#pragma unroll
    for (int off = 1; off < 64; off <<= 1) {
        int t = __shfl_up(v, off);
        if (lane >= off) v += t;
    }
    return v;
}

__global__ __launch_bounds__(256) void csr_scan(
    const int* __restrict__ cnts, int* __restrict__ boff, int* __restrict__ cbase,
    int* __restrict__ row_ptr, int NB, int N, int E)
{
    __shared__ int wsum[4];
    int t = threadIdx.x, lane = t & 63, w = t >> 6;
    int sum = 0;
    if (t < NB)
        for (int k = 0; k < NBLK; ++k) sum += cnts[k * NB + t];
    int incl = wave_incl_scan(sum, lane);
    if (lane == 63) wsum[w] = incl;
    __syncthreads();
    int wo = 0;
    for (int i = 0; i < w; ++i) wo += wsum[i];
    int excl = wo + incl - sum;
    if (t < NB) {
        boff[t] = excl;
        int run = excl;
        for (int k = 0; k < NBLK; ++k) {
            cbase[k * NB + t] = run;
            run += cnts[k * NB + t];
        }
    }
    if (t == 0) { boff[NB] = E; row_ptr[N] = E; }
}

__global__ __launch_bounds__(512) void chunk_scatter(
    const int4* __restrict__ dst4, const int4* __restrict__ src4,
    const int* __restrict__ dst, const int* __restrict__ src,
    const int* __restrict__ cbase, int* __restrict__ ebuf,
    int NB, int E4, int E, int C4)
{
    __shared__ int lcur[NBMAX];
    int k = blockIdx.x, tid = threadIdx.x;
    for (int i = tid; i < NB; i += 512) lcur[i] = cbase[k * NB + i];
    __syncthreads();
    int i0 = k * C4, i1 = min(i0 + C4, E4);
    for (int i = i0 + tid; i < i1; i += 512) {
        int4 d = dst4[i];
        int4 s = src4[i];
        int b, p;
        b = d.x >> BSH; p = atomicAdd(&lcur[b], 1); ebuf[p] = ((d.x & (BN - 1)) << 24) | s.x;
        b = d.y >> BSH; p = atomicAdd(&lcur[b], 1); ebuf[p] = ((d.y & (BN - 1)) << 24) | s.y;
        b = d.z >> BSH; p = atomicAdd(&lcur[b], 1); ebuf[p] = ((d.z & (BN - 1)) << 24) | s.z;
        b = d.w >> BSH; p = atomicAdd(&lcur[b], 1); ebuf[p] = ((d.w & (BN - 1)) << 24) | s.w;
    }
    if (k == NBLK - 1) {
        for (int e = E4 * 4 + tid; e < E; e += 512) {
            int d = dst[e];
            int b = d >> BSH;
            int p = atomicAdd(&lcur[b], 1);
            ebuf[p] = ((d & (BN - 1)) << 24) | src[e];
        }
    }
}

__global__ __launch_bounds__(512) void group_build(
    const int* __restrict__ ebuf, const int* __restrict__ boff,
    int* __restrict__ row_ptr, int* __restrict__ col, int N)
{
    __shared__ int lcnt[BN];
    __shared__ int loff[BN];
    __shared__ int lcur[BN];
    __shared__ int wsum[4];
    __shared__ int stage[STAGE_CAP];
    int b = blockIdx.x, tid = threadIdx.x;
    int e0 = boff[b], e1 = boff[b + 1];
    int total = e1 - e0;
    if (tid < BN) { lcnt[tid] = 0; lcur[tid] = 0; }
    __syncthreads();
    for (int e = e0 + tid; e < e1; e += 512)
        atomicAdd(&lcnt[((unsigned)ebuf[e]) >> 24], 1);
    __syncthreads();
    int lane = tid & 63, w = tid >> 6;
    int v = (tid < BN) ? lcnt[tid] : 0;
    int incl = wave_incl_scan(v, lane);
    if (tid < BN && lane == 63) wsum[w] = incl;
    __syncthreads();
    if (tid < BN) {
        int wo = 0;
        for (int i = 0; i < w; ++i) wo += wsum[i];
        int excl = wo + incl - v;
        loff[tid] = excl;
        int node = b * BN + tid;
        if (node < N) row_ptr[node] = e0 + excl;
    }
    __syncthreads();
    if (total <= STAGE_CAP) {
        for (int e = e0 + tid; e < e1; e += 512) {
            int p = ebuf[e];
            int dl = ((unsigned)p) >> 24;
            int r = atomicAdd(&lcur[dl], 1);
            stage[loff[dl] + r] = p & 0xFFFFFF;
        }
        __syncthreads();
        for (int i = tid; i < total; i += 512)
            col[e0 + i] = stage[i];
    } else {
        for (int e = e0 + tid; e < e1; e += 512) {
            int p = ebuf[e];
            int dl = ((unsigned)p) >> 24;
            int r = atomicAdd(&lcur[dl], 1);
            col[e0 + loff[dl] + r] = p & 0xFFFFFF;
        }
    }
}

// ---------------------------------------------------------------------------
// Aggregate v3: single-pass online softmax + relu + residual.
// Wave per node; 8 edge-slots (es) x 8 feature-lanes (fl); lane loads bf16x8.
// No LDS. Flash-style (m,s,acc) merge across slots via xor shuffles.
// ---------------------------------------------------------------------------
__global__ __launch_bounds__(256) void aggregate(
    const uint4* __restrict__ hxq, const int* __restrict__ row_ptr,
    const int* __restrict__ col, const float* __restrict__ sarr,
    const float* __restrict__ darr, const float* __restrict__ bias,
    float* __restrict__ h, int n)
{
    int tid = threadIdx.x;
    int wid = tid >> 6, lane = tid & 63;
    int fl = lane & 7, es = lane >> 3;
    int v = blockIdx.x * 4 + wid;
    if (v >= n) return;

    int beg = row_ptr[v], end = row_ptr[v + 1];
    float adi = darr[v];
    float m = -3.4e38f, s = 0.f;
    float acc[8];
#pragma unroll
    for (int j = 0; j < 8; ++j) acc[j] = 0.f;

    for (int e = beg + es; e < end; e += 8) {
        int c = col[e];
        float a = sarr[c] + adi;
        a = a > 0.f ? a : NEG_SLOPE * a;
        uint4 u = hxq[c * 8 + fl];
        float mN = fmaxf(m, a);
        float f = __expf(m - mN);
        float wgt = __expf(a - mN);
        m = mN;
        s = s * f + wgt;
        float p0 = __uint_as_float(u.x << 16);
        float p1 = __uint_as_float(u.x & 0xffff0000u);
        float p2 = __uint_as_float(u.y << 16);
        float p3 = __uint_as_float(u.y & 0xffff0000u);
        float p4 = __uint_as_float(u.z << 16);
        float p5 = __uint_as_float(u.z & 0xffff0000u);
        float p6 = __uint_as_float(u.w << 16);
        float p7 = __uint_as_float(u.w & 0xffff0000u);
        acc[0] = acc[0] * f + wgt * p0;
        acc[1] = acc[1] * f + wgt * p1;
        acc[2] = acc[2] * f + wgt * p2;
        acc[3] = acc[3] * f + wgt * p3;
        acc[4] = acc[4] * f + wgt * p4;
        acc[5] = acc[5] * f + wgt * p5;
        acc[6] = acc[6] * f + wgt * p6;
        acc[7] = acc[7] * f + wgt * p7;
    }

    // merge the 8 slots (lane bits 3,4,5); sentinel -3.4e38 keeps exp finite
#pragma unroll
    for (int off = 8; off < 64; off <<= 1) {
        float m2 = __shfl_xor(m, off);
        float s2 = __shfl_xor(s, off);
        float mN = fmaxf(m, m2);
        float f1 = __expf(m - mN);
        float f2 = __expf(m2 - mN);
        s = s * f1 + s2 * f2;
#pragma unroll
        for (int j = 0; j < 8; ++j) {
            float a2 = __shfl_xor(acc[j], off);
            acc[j] = acc[j] * f1 + a2 * f2;
        }
        m = mN;
    }

    if (es == 0) {
        float inv = (s > 0.f) ? 1.f / s : 0.f;
        float* hp = &h[v * DD + fl * 8];
        float4 c0 = *(float4*)hp;
        float4 c1 = *(float4*)(hp + 4);
        const float* bp = &bias[fl * 8];
        float4 b0 = *(const float4*)bp;
        float4 b1 = *(const float4*)(bp + 4);
        c0.x += fmaxf(acc[0] * inv + b0.x, 0.f);
        c0.y += fmaxf(acc[1] * inv + b0.y, 0.f);
        c0.z += fmaxf(acc[2] * inv + b0.z, 0.f);
        c0.w += fmaxf(acc[3] * inv + b0.w, 0.f);
        c1.x += fmaxf(acc[4] * inv + b1.x, 0.f);
        c1.y += fmaxf(acc[5] * inv + b1.y, 0.f);
        c1.z += fmaxf(acc[6] * inv + b1.z, 0.f);
        c1.w += fmaxf(acc[7] * inv + b1.w, 0.f);
        *(float4*)hp = c0;
        *(float4*)(hp + 4) = c1;
    }
}

// ---------------------------------------------------------------------------
extern "C" void kernel_launch(void* const* d_in, const int* in_sizes, int n_in,
                              void* d_out, int out_size, void* d_ws, size_t ws_size,
                              hipStream_t stream)
{
    const float* x  = (const float*)d_in[0];
    const int*   ei = (const int*)d_in[1];
    const float* W0 = (const float*)d_in[4];
    const float* b0 = (const float*)d_in[5];
    const float* W1 = (const float*)d_in[6];
    const float* as1= (const float*)d_in[7];
    const float* ad1= (const float*)d_in[8];
    const float* b1 = (const float*)d_in[9];
    const float* W2 = (const float*)d_in[10];
    const float* as2= (const float*)d_in[11];
    const float* ad2= (const float*)d_in[12];
    const float* b2 = (const float*)d_in[13];

    int N = in_sizes[0] / DD;
    int E = in_sizes[1] / 2;
    int E4 = E >> 2;
    int C4 = (E4 + NBLK - 1) / NBLK;
    int NB = (N + BN - 1) >> BSH;
    float* h = (float*)d_out;

    ushort4* hxb4 = (ushort4*)d_ws;                      // N*16 ushort4 (6.4 MB)
    float* sarr   = (float*)(hxb4 + (size_t)N * 16);     // N
    float* darr   = sarr + N;                            // N
    int*   row_ptr= (int*)(darr + N);                    // N+1
    int*   cnts   = row_ptr + (N + 1);                   // NBLK*NB
    int*   cbase  = cnts + NBLK * NB;                    // NBLK*NB
    int*   boff   = cbase + NBLK * NB;                   // NB+1
    int*   ebuf   = boff + (NB + 1);                     // E
    int*   colb   = ebuf + E;                            // E

    const int* src = ei;
    const int* dst = ei + E;
    const int4* dst4 = (const int4*)dst;
    const int4* src4 = (const int4*)src;

    int mm_tiles = (N + 63) / 64;
    int agg_blks = (N + 3) / 4;

    // ---- K1: chunk_count + mm_fused (independent, co-scheduled) ----
    k1_count_mm<<<NBLK + mm_tiles, 256, 0, stream>>>(
        dst4, dst, cnts, NB, E4, E, C4,
        x, W0, b0, W1, as1, ad1, h, hxb4, sarr, darr, N);

    // ---- CSR build remainder ----
    csr_scan<<<1, 256, 0, stream>>>(cnts, boff, cbase, row_ptr, NB, N, E);
    chunk_scatter<<<NBLK, 512, 0, stream>>>(dst4, src4, dst, src, cbase, ebuf, NB, E4, E, C4);
    group_build<<<NB, 512, 0, stream>>>(ebuf, boff, row_ptr, colb, N);

    // ---- GAT layer 1 aggregate ----
    aggregate<<<agg_blks, 256, 0, stream>>>((const uint4*)hxb4, row_ptr, colb, sarr, darr, b1, h, N);

    // ---- GAT layer 2 ----
    mm_gat<<<mm_tiles, 256, 0, stream>>>(h, W2, as2, ad2, hxb4, sarr, darr, N);
    aggregate<<<agg_blks, 256, 0, stream>>>((const uint4*)hxb4, row_ptr, colb, sarr, darr, b2, h, N);
}